// Round 4
// baseline (3198.784 us; speedup 1.0000x reference)
//
#include <hip/hip_runtime.h>
#include <math.h>

static constexpr int kS  = 8400;
static constexpr int kNB = 32;
static constexpr int kH  = 256;
static constexpr int kC  = 80;
static constexpr int kQ  = 300;

// output offsets (fp32 elements) in return order
static constexpr size_t OFF_TGT = 0;
static constexpr size_t OFF_REF = (size_t)kNB * kQ * kH;
static constexpr size_t OFF_BOX = OFF_REF + (size_t)kNB * kQ * 4;
static constexpr size_t OFF_LOG = OFF_BOX + (size_t)kNB * kQ * 4;
static constexpr size_t OFF_MSK = OFF_LOG + (size_t)kNB * kQ * kC;

__device__ __forceinline__ bool valid_s(int s) {
  if (s < 6400) {
    int y = s / 80; int x = s - y * 80;
    return (x >= 1) && (x <= 78) && (y >= 1) && (y <= 78);
  }
  return true;
}

__device__ __forceinline__ float anchor_component(int s, int c) {
  int lvl, W, x, y;
  if (s < 6400)      { lvl = 0; W = 80; y = s / 80;              x = s - y * 80; }
  else if (s < 8000) { lvl = 1; W = 40; int u = s - 6400; y = u / 40; x = u - y * 40; }
  else               { lvl = 2; W = 20; int u = s - 8000; y = u / 20; x = u - y * 20; }
  float v;
  if (c == 0)      v = ((float)x + 0.5f) / (float)W;
  else if (c == 1) v = ((float)y + 0.5f) / (float)W;
  else             v = 0.05f * (float)(1 << lvl);
  v = fminf(fmaxf(v, 1e-4f), 1.0f - 1e-4f);
  return logf(v / (1.0f - v));
}

__device__ __forceinline__ unsigned long long key64(double d) {
  unsigned long long u = (unsigned long long)__double_as_longlong(d);
  return u ^ ((unsigned long long)((long long)u >> 63) | 0x8000000000000000ULL);
}

// ===================== kernel A: fp64 encode + score + rowmax =====================
// 16 rows per block, 256 threads. Ranking path fully fp64-accurate.
extern "C" __global__ __launch_bounds__(256)
void k_encode(const float* __restrict__ mem, const float* __restrict__ pw,
              const float* __restrict__ pb, const float* __restrict__ g,
              const float* __restrict__ bt, const float* __restrict__ sw,
              const float* __restrict__ sb,
              float* __restrict__ out_masked, double* __restrict__ rowmax)
{
  __shared__ float a_lds[16 * 256];   // input tile, later encoded-hi
  __shared__ float w_lds[256 * 32];   // weight chunk; first 16KB later encoded-lo
  const int t = threadIdx.x;
  const int m0 = blockIdx.x * 16;

  // stage 16 rows (masked) + write masked_memory
#pragma unroll
  for (int i = 0; i < 4; ++i) {
    int f4 = i * 256 + t;
    int r = f4 >> 6, k4 = f4 & 63;
    int m = m0 + r;
    int s = m % kS;
    float4 v = *(const float4*)(mem + (size_t)m * 256 + k4 * 4);
    if (!valid_s(s)) { v.x = 0.f; v.y = 0.f; v.z = 0.f; v.w = 0.f; }
    *(float4*)(a_lds + r * 256 + k4 * 4) = v;
    *(float4*)(out_masked + (size_t)m * 256 + k4 * 4) = v;
  }
  __syncthreads();

  // proj GEMM: thread (rg=t>>5, cg=t&31) owns rows rg*2..+1, cols cg+32*cc, f64 acc
  const int rg = t >> 5, cg = t & 31;
  double acc[2][8];
#pragma unroll
  for (int rr = 0; rr < 2; ++rr)
#pragma unroll
    for (int cc = 0; cc < 8; ++cc) acc[rr][cc] = 0.0;

#pragma unroll 1
  for (int kc = 0; kc < 8; ++kc) {
#pragma unroll
    for (int i = 0; i < 8; ++i) {
      int e4 = i * 256 + t;
      int c = e4 >> 3, k4 = e4 & 7;
      float4 v = *(const float4*)(pw + c * 256 + kc * 32 + k4 * 4);
      *(float4*)(w_lds + c * 32 + ((k4 ^ (c & 7)) << 2)) = v;
    }
    __syncthreads();
#pragma unroll
    for (int k4 = 0; k4 < 8; ++k4) {
      float4 av[2];
#pragma unroll
      for (int rr = 0; rr < 2; ++rr)
        av[rr] = *(const float4*)(a_lds + (rg * 2 + rr) * 256 + kc * 32 + k4 * 4);
#pragma unroll
      for (int cc = 0; cc < 8; ++cc) {
        int c = cg + (cc << 5);
        float4 wv = *(const float4*)(w_lds + c * 32 + ((k4 ^ (c & 7)) << 2));
#pragma unroll
        for (int rr = 0; rr < 2; ++rr) {
          acc[rr][cc] = fma((double)av[rr].x, (double)wv.x, acc[rr][cc]);
          acc[rr][cc] = fma((double)av[rr].y, (double)wv.y, acc[rr][cc]);
          acc[rr][cc] = fma((double)av[rr].z, (double)wv.z, acc[rr][cc]);
          acc[rr][cc] = fma((double)av[rr].w, (double)wv.w, acc[rr][cc]);
        }
      }
    }
    __syncthreads();
  }

  // bias + LayerNorm in fp64 (row spread over 32 lanes)
#pragma unroll
  for (int rr = 0; rr < 2; ++rr) {
#pragma unroll
    for (int cc = 0; cc < 8; ++cc) acc[rr][cc] += (double)pb[cg + (cc << 5)];
    double s = 0.0;
#pragma unroll
    for (int cc = 0; cc < 8; ++cc) s += acc[rr][cc];
    s += __shfl_xor(s, 1); s += __shfl_xor(s, 2); s += __shfl_xor(s, 4);
    s += __shfl_xor(s, 8); s += __shfl_xor(s, 16);
    double mu = s * (1.0 / 256.0);
    double v = 0.0;
#pragma unroll
    for (int cc = 0; cc < 8; ++cc) { double d = acc[rr][cc] - mu; v += d * d; }
    v += __shfl_xor(v, 1); v += __shfl_xor(v, 2); v += __shfl_xor(v, 4);
    v += __shfl_xor(v, 8); v += __shfl_xor(v, 16);
    double rs = 1.0 / sqrt(v * (1.0 / 256.0) + 1e-5);
#pragma unroll
    for (int cc = 0; cc < 8; ++cc) {
      int c = cg + (cc << 5);
      acc[rr][cc] = (acc[rr][cc] - mu) * rs * (double)g[c] + (double)bt[c];
    }
  }

  // store encoded as hi/lo fp32 split (exact to ~2^-48 rel)
  float* hi_lds = a_lds;
  float* lo_lds = w_lds;  // first 16KB of w_lds
#pragma unroll
  for (int rr = 0; rr < 2; ++rr)
#pragma unroll
    for (int cc = 0; cc < 8; ++cc) {
      int idx = (rg * 2 + rr) * 256 + cg + (cc << 5);
      float h = (float)acc[rr][cc];
      hi_lds[idx] = h;
      lo_lds[idx] = (float)(acc[rr][cc] - (double)h);
    }
  __syncthreads();

  // score GEMM fp64: thread (row=t>>4, cq=t&15) -> full dot for 5 classes
  const int row = t >> 4, cq = t & 15;
  double acc2[5] = {0.0, 0.0, 0.0, 0.0, 0.0};
#pragma unroll 4
  for (int k4 = 0; k4 < 64; ++k4) {
    float4 hv = *(const float4*)(hi_lds + row * 256 + k4 * 4);
    float4 lv = *(const float4*)(lo_lds + row * 256 + k4 * 4);
#pragma unroll
    for (int cc = 0; cc < 5; ++cc) {
      int c = cq * 5 + cc;
      float4 wv = *(const float4*)(sw + c * 256 + k4 * 4);
      acc2[cc] = fma((double)hv.x, (double)wv.x, fma((double)lv.x, (double)wv.x, acc2[cc]));
      acc2[cc] = fma((double)hv.y, (double)wv.y, fma((double)lv.y, (double)wv.y, acc2[cc]));
      acc2[cc] = fma((double)hv.z, (double)wv.z, fma((double)lv.z, (double)wv.z, acc2[cc]));
      acc2[cc] = fma((double)hv.w, (double)wv.w, fma((double)lv.w, (double)wv.w, acc2[cc]));
    }
  }
  double rmax = -1.0e300;
#pragma unroll
  for (int cc = 0; cc < 5; ++cc) {
    double sc = acc2[cc] + (double)sb[cq * 5 + cc];
    rmax = fmax(rmax, sc);
  }
  rmax = fmax(rmax, __shfl_xor(rmax, 1));
  rmax = fmax(rmax, __shfl_xor(rmax, 2));
  rmax = fmax(rmax, __shfl_xor(rmax, 4));
  rmax = fmax(rmax, __shfl_xor(rmax, 8));
  if (cq == 0) rowmax[m0 + row] = rmax;
}

// ===================== kernel B: exact top-300 on fp64 keys =====================
extern "C" __global__ __launch_bounds__(1024)
void k_topk(const double* __restrict__ rowmax, int* __restrict__ topk)
{
  __shared__ unsigned int hi[kS];
  __shared__ unsigned long long ckey[1024];
  __shared__ unsigned int cidx[1024];
  __shared__ int red[16];
  __shared__ int sTotal;
  __shared__ int sCnt;
  const int t = threadIdx.x;
  const int b = blockIdx.x;

  for (int i = t; i < kS; i += 1024)
    hi[i] = (unsigned int)(key64(rowmax[(size_t)b * kS + i]) >> 32);
  __syncthreads();

  // radix select on hi words: H = hi-value of the 300th largest hi
  unsigned int H = 0;
  for (int bit = 31; bit >= 0; --bit) {
    unsigned int cand = H | (1u << bit);
    int local = 0;
    for (int i = t; i < kS; i += 1024) local += (hi[i] >= cand) ? 1 : 0;
#pragma unroll
    for (int msk = 1; msk <= 32; msk <<= 1) local += __shfl_xor(local, msk);
    if ((t & 63) == 0) red[t >> 6] = local;
    __syncthreads();
    if (t < 16) {
      int v = red[t];
#pragma unroll
      for (int msk = 1; msk <= 8; msk <<= 1) v += __shfl_xor(v, msk);
      if (t == 0) sTotal = v;
    }
    __syncthreads();
    if (sTotal >= kQ) H = cand;
    __syncthreads();
  }

  if (t == 0) sCnt = 0;
  __syncthreads();
  for (int i = t; i < kS; i += 1024) {
    if (hi[i] >= H) {
      int p = atomicAdd(&sCnt, 1);
      if (p < 1024) {
        ckey[p] = key64(rowmax[(size_t)b * kS + i]);
        cidx[p] = (unsigned int)i;
      }
    }
  }
  __syncthreads();
  int cnt = sCnt; if (cnt > 1024) cnt = 1024;
  if (t >= cnt) { ckey[t] = 0ull; cidx[t] = 0xFFFFFFFFu; }
  __syncthreads();

  // bitonic sort: descending by key; equal key -> ascending index (lax.top_k)
  for (int ksz = 2; ksz <= 1024; ksz <<= 1) {
    for (int j = ksz >> 1; j > 0; j >>= 1) {
      int ixj = t ^ j;
      if (ixj > t) {
        unsigned long long ka = ckey[t], kb = ckey[ixj];
        unsigned int ia = cidx[t], ib = cidx[ixj];
        bool desc = ((t & ksz) == 0);
        bool lessAB = (ka < kb) || (ka == kb && ia > ib);
        bool lessBA = (kb < ka) || (ka == kb && ib > ia);
        bool do_swap = desc ? lessAB : lessBA;
        if (do_swap) { ckey[t] = kb; ckey[ixj] = ka; cidx[t] = ib; cidx[ixj] = ia; }
      }
      __syncthreads();
    }
  }
  if (t < kQ) topk[b * kQ + t] = (int)cidx[t];
}

// ===================== fp32 helpers for kernel C =====================
__device__ __forceinline__ void gemm_nk256(const float* __restrict__ W,
                                           const float* __restrict__ a_lds,
                                           float* __restrict__ w_lds,
                                           float acc[4][8], int rg, int cg, int t)
{
#pragma unroll
  for (int rr = 0; rr < 4; ++rr)
#pragma unroll
    for (int cc = 0; cc < 8; ++cc) acc[rr][cc] = 0.0f;

#pragma unroll 1
  for (int kc = 0; kc < 8; ++kc) {
#pragma unroll
    for (int i = 0; i < 8; ++i) {
      int e4 = i * 256 + t;
      int c = e4 >> 3, k4 = e4 & 7;
      float4 v = *(const float4*)(W + c * 256 + kc * 32 + k4 * 4);
      *(float4*)(w_lds + c * 32 + ((k4 ^ (c & 7)) << 2)) = v;
    }
    __syncthreads();
#pragma unroll
    for (int k4 = 0; k4 < 8; ++k4) {
      float4 av[4];
#pragma unroll
      for (int rr = 0; rr < 4; ++rr)
        av[rr] = *(const float4*)(a_lds + (rg * 4 + rr) * 256 + kc * 32 + k4 * 4);
#pragma unroll
      for (int cc = 0; cc < 8; ++cc) {
        int c = cg + (cc << 5);
        float4 wv = *(const float4*)(w_lds + c * 32 + ((k4 ^ (c & 7)) << 2));
#pragma unroll
        for (int rr = 0; rr < 4; ++rr) {
          acc[rr][cc] = fmaf(av[rr].x, wv.x, acc[rr][cc]);
          acc[rr][cc] = fmaf(av[rr].y, wv.y, acc[rr][cc]);
          acc[rr][cc] = fmaf(av[rr].z, wv.z, acc[rr][cc]);
          acc[rr][cc] = fmaf(av[rr].w, wv.w, acc[rr][cc]);
        }
      }
    }
    __syncthreads();
  }
}

__device__ __forceinline__ void gemm_score(const float* __restrict__ SW,
                                           const float* __restrict__ a_lds,
                                           float* __restrict__ w_lds,
                                           float acc2[2][5], int rg2, int cq, int t)
{
#pragma unroll
  for (int rr = 0; rr < 2; ++rr)
#pragma unroll
    for (int cc = 0; cc < 5; ++cc) acc2[rr][cc] = 0.0f;

#pragma unroll 1
  for (int kc = 0; kc < 8; ++kc) {
#pragma unroll
    for (int i = 0; i < 3; ++i) {
      int e4 = i * 256 + t;
      if (e4 < 640) {
        int c = e4 >> 3, k4 = e4 & 7;
        float4 v = *(const float4*)(SW + c * 256 + kc * 32 + k4 * 4);
        *(float4*)(w_lds + c * 32 + ((k4 ^ (c & 7)) << 2)) = v;
      }
    }
    __syncthreads();
#pragma unroll
    for (int k4 = 0; k4 < 8; ++k4) {
      float4 ev[2];
      ev[0] = *(const float4*)(a_lds + (rg2 * 2 + 0) * 256 + kc * 32 + k4 * 4);
      ev[1] = *(const float4*)(a_lds + (rg2 * 2 + 1) * 256 + kc * 32 + k4 * 4);
#pragma unroll
      for (int cc = 0; cc < 5; ++cc) {
        int c = cq * 5 + cc;
        float4 wv = *(const float4*)(w_lds + c * 32 + ((k4 ^ (c & 7)) << 2));
#pragma unroll
        for (int rr = 0; rr < 2; ++rr) {
          acc2[rr][cc] = fmaf(ev[rr].x, wv.x, acc2[rr][cc]);
          acc2[rr][cc] = fmaf(ev[rr].y, wv.y, acc2[rr][cc]);
          acc2[rr][cc] = fmaf(ev[rr].z, wv.z, acc2[rr][cc]);
          acc2[rr][cc] = fmaf(ev[rr].w, wv.w, acc2[rr][cc]);
        }
      }
    }
    __syncthreads();
  }
}

__device__ __forceinline__ void apply_ln(float acc[4][8], const float* __restrict__ g,
                                         const float* __restrict__ bt, int cg)
{
#pragma unroll
  for (int rr = 0; rr < 4; ++rr) {
    float s = 0.0f;
#pragma unroll
    for (int cc = 0; cc < 8; ++cc) s += acc[rr][cc];
    s += __shfl_xor(s, 1); s += __shfl_xor(s, 2); s += __shfl_xor(s, 4);
    s += __shfl_xor(s, 8); s += __shfl_xor(s, 16);
    float mu = s * (1.0f / 256.0f);
    float v = 0.0f;
#pragma unroll
    for (int cc = 0; cc < 8; ++cc) { float d = acc[rr][cc] - mu; v += d * d; }
    v += __shfl_xor(v, 1); v += __shfl_xor(v, 2); v += __shfl_xor(v, 4);
    v += __shfl_xor(v, 8); v += __shfl_xor(v, 16);
    float rs = 1.0f / sqrtf(v * (1.0f / 256.0f) + 1e-5f);
#pragma unroll
    for (int cc = 0; cc < 8; ++cc) {
      int c = cg + (cc << 5);
      acc[rr][cc] = (acc[rr][cc] - mu) * rs * g[c] + bt[c];
    }
  }
}

// ===================== kernel C: gathered re-encode + box MLP + outputs =====================
extern "C" __global__ __launch_bounds__(256)
void k_boxes(const float* __restrict__ mem, const int* __restrict__ topk,
             const float* __restrict__ pw, const float* __restrict__ pb,
             const float* __restrict__ g, const float* __restrict__ bt,
             const float* __restrict__ sw, const float* __restrict__ sb,
             const float* __restrict__ w1, const float* __restrict__ b1,
             const float* __restrict__ w2, const float* __restrict__ b2,
             const float* __restrict__ w3, const float* __restrict__ b3,
             float* __restrict__ out_tgt, float* __restrict__ out_ref,
             float* __restrict__ out_box, float* __restrict__ out_log)
{
  __shared__ float a_lds[32 * 256];
  __shared__ float w_lds[256 * 32];
  const int t = threadIdx.x;
  const int r0g = blockIdx.x * 32;

#pragma unroll
  for (int i = 0; i < 8; ++i) {
    int f4 = i * 256 + t;
    int r = f4 >> 6, k4 = f4 & 63;
    int rgid = r0g + r;
    int bb = rgid / kQ;
    int s = topk[rgid];
    float4 v = *(const float4*)(mem + ((size_t)bb * kS + s) * 256 + k4 * 4);
    if (!valid_s(s)) { v.x = 0.f; v.y = 0.f; v.z = 0.f; v.w = 0.f; }
    *(float4*)(a_lds + r * 256 + k4 * 4) = v;
  }

  const int rg = t >> 5, cg = t & 31;
  float acc[4][8];
  gemm_nk256(pw, a_lds, w_lds, acc, rg, cg, t);
#pragma unroll
  for (int rr = 0; rr < 4; ++rr)
#pragma unroll
    for (int cc = 0; cc < 8; ++cc) acc[rr][cc] += pb[cg + (cc << 5)];
  apply_ln(acc, g, bt, cg);
#pragma unroll
  for (int rr = 0; rr < 4; ++rr)
#pragma unroll
    for (int cc = 0; cc < 8; ++cc)
      a_lds[(rg * 4 + rr) * 256 + cg + (cc << 5)] = acc[rr][cc];
  __syncthreads();

#pragma unroll
  for (int i = 0; i < 8; ++i) {
    int f4 = i * 256 + t;
    int r = f4 >> 6, k4 = f4 & 63;
    *(float4*)(out_tgt + (size_t)(r0g + r) * 256 + k4 * 4) =
        *(const float4*)(a_lds + r * 256 + k4 * 4);
  }

  const int rg2 = t >> 4, cq = t & 15;
  float acc2[2][5];
  gemm_score(sw, a_lds, w_lds, acc2, rg2, cq, t);
#pragma unroll
  for (int rr = 0; rr < 2; ++rr)
#pragma unroll
    for (int cc = 0; cc < 5; ++cc) {
      int c = cq * 5 + cc;
      out_log[(size_t)(r0g + rg2 * 2 + rr) * kC + c] = acc2[rr][cc] + sb[c];
    }

  gemm_nk256(w1, a_lds, w_lds, acc, rg, cg, t);
#pragma unroll
  for (int rr = 0; rr < 4; ++rr)
#pragma unroll
    for (int cc = 0; cc < 8; ++cc) {
      float v = acc[rr][cc] + b1[cg + (cc << 5)];
      a_lds[(rg * 4 + rr) * 256 + cg + (cc << 5)] = fmaxf(v, 0.0f);
    }
  __syncthreads();

  gemm_nk256(w2, a_lds, w_lds, acc, rg, cg, t);
#pragma unroll
  for (int rr = 0; rr < 4; ++rr)
#pragma unroll
    for (int cc = 0; cc < 8; ++cc) {
      float v = acc[rr][cc] + b2[cg + (cc << 5)];
      a_lds[(rg * 4 + rr) * 256 + cg + (cc << 5)] = fmaxf(v, 0.0f);
    }
  __syncthreads();

  if (t < 128) {
    int r = t >> 2, c = t & 3;
    float accb = 0.0f;
#pragma unroll 4
    for (int k4 = 0; k4 < 64; ++k4) {
      float4 hv = *(const float4*)(a_lds + r * 256 + k4 * 4);
      float4 wv = *(const float4*)(w3 + c * 256 + k4 * 4);
      accb = fmaf(hv.x, wv.x, accb);
      accb = fmaf(hv.y, wv.y, accb);
      accb = fmaf(hv.z, wv.z, accb);
      accb = fmaf(hv.w, wv.w, accb);
    }
    int rgid = r0g + r;
    int s = topk[rgid];
    float bu = accb + b3[c] + anchor_component(s, c);
    out_ref[(size_t)rgid * 4 + c] = bu;
    out_box[(size_t)rgid * 4 + c] = 1.0f / (1.0f + expf(-bu));
  }
}

extern "C" void kernel_launch(void* const* d_in, const int* in_sizes, int n_in,
                              void* d_out, int out_size, void* d_ws, size_t ws_size,
                              hipStream_t stream) {
  (void)in_sizes; (void)n_in; (void)out_size; (void)ws_size;
  const float* mem = (const float*)d_in[0];
  const float* pw = (const float*)d_in[2];
  const float* pb = (const float*)d_in[3];
  const float* g  = (const float*)d_in[4];
  const float* bt = (const float*)d_in[5];
  const float* sw = (const float*)d_in[6];
  const float* sb = (const float*)d_in[7];
  const float* w1 = (const float*)d_in[8];
  const float* b1 = (const float*)d_in[9];
  const float* w2 = (const float*)d_in[10];
  const float* b2 = (const float*)d_in[11];
  const float* w3 = (const float*)d_in[12];
  const float* b3 = (const float*)d_in[13];

  float* out = (float*)d_out;
  float* out_tgt = out + OFF_TGT;
  float* out_ref = out + OFF_REF;
  float* out_box = out + OFF_BOX;
  float* out_log = out + OFF_LOG;
  float* out_msk = out + OFF_MSK;

  double* rowmax = (double*)d_ws;
  int*    topk   = (int*)((char*)d_ws + (size_t)kNB * kS * sizeof(double));

  k_encode<<<dim3(kNB * kS / 16), dim3(256), 0, stream>>>(mem, pw, pb, g, bt, sw, sb,
                                                          out_msk, rowmax);
  k_topk<<<dim3(kNB), dim3(1024), 0, stream>>>(rowmax, topk);
  k_boxes<<<dim3(kNB * kQ / 32), dim3(256), 0, stream>>>(mem, topk, pw, pb, g, bt, sw, sb,
                                                         w1, b1, w2, b2, w3, b3,
                                                         out_tgt, out_ref, out_box, out_log);
}

// Round 8
// 1809.094 us; speedup vs baseline: 1.7682x; 1.7682x over previous
//
#include <hip/hip_runtime.h>
#include <math.h>

static constexpr int kS  = 8400;
static constexpr int kNB = 32;
static constexpr int kH  = 256;
static constexpr int kC  = 80;
static constexpr int kQ  = 300;
static constexpr int kCandCap = 1024;

// output offsets (fp32 elements) in return order
static constexpr size_t OFF_TGT = 0;
static constexpr size_t OFF_REF = (size_t)kNB * kQ * kH;
static constexpr size_t OFF_BOX = OFF_REF + (size_t)kNB * kQ * 4;
static constexpr size_t OFF_LOG = OFF_BOX + (size_t)kNB * kQ * 4;
static constexpr size_t OFF_MSK = OFF_LOG + (size_t)kNB * kQ * kC;

__device__ __forceinline__ bool valid_s(int s) {
  if (s < 6400) {
    int y = s / 80; int x = s - y * 80;
    return (x >= 1) && (x <= 78) && (y >= 1) && (y <= 78);
  }
  return true;
}

__device__ __forceinline__ float anchor_component(int s, int c) {
  int lvl, W, x, y;
  if (s < 6400)      { lvl = 0; W = 80; y = s / 80;              x = s - y * 80; }
  else if (s < 8000) { lvl = 1; W = 40; int u = s - 6400; y = u / 40; x = u - y * 40; }
  else               { lvl = 2; W = 20; int u = s - 8000; y = u / 20; x = u - y * 20; }
  float v;
  if (c == 0)      v = ((float)x + 0.5f) / (float)W;
  else if (c == 1) v = ((float)y + 0.5f) / (float)W;
  else             v = 0.05f * (float)(1 << lvl);
  v = fminf(fmaxf(v, 1e-4f), 1.0f - 1e-4f);
  return logf(v / (1.0f - v));
}

__device__ __forceinline__ unsigned long long key64(double d) {
  unsigned long long u = (unsigned long long)__double_as_longlong(d);
  return u ^ ((unsigned long long)((long long)u >> 63) | 0x8000000000000000ULL);
}

__device__ __forceinline__ unsigned int key32(float f) {
  unsigned int u = __float_as_uint(f);
  return u ^ ((unsigned int)((int)u >> 31) | 0x80000000u);
}

__device__ __forceinline__ float dec32(unsigned int k) {
  unsigned int u = (k & 0x80000000u) ? (k ^ 0x80000000u) : ~k;
  return __uint_as_float(u);
}

// ===================== Pass A: fp32 encode + score + rowmax (screening) ===============
// 32 rows/block, 256 threads, 16-wide K chunks. LDS 48KB -> 3 blocks/CU.
extern "C" __global__ __launch_bounds__(256)
void k_encode32(const float* __restrict__ mem, const float* __restrict__ pw,
                const float* __restrict__ pb, const float* __restrict__ g,
                const float* __restrict__ bt, const float* __restrict__ sw,
                const float* __restrict__ sb,
                float* __restrict__ out_masked, float* __restrict__ rowmax32)
{
  __shared__ float a_lds[32 * 256];  // 32KB: input tile, then encoded
  __shared__ float w_lds[256 * 16];  // 16KB: weight K-chunk (swizzled float4)
  const int t = threadIdx.x;
  const int m0 = blockIdx.x * 32;

  // stage 32 rows (masked) + write masked_memory
#pragma unroll
  for (int i = 0; i < 8; ++i) {
    int f4 = i * 256 + t;
    int r = f4 >> 6, k4 = f4 & 63;
    int m = m0 + r;
    int s = m % kS;
    float4 v = *(const float4*)(mem + (size_t)m * 256 + k4 * 4);
    if (!valid_s(s)) { v.x = 0.f; v.y = 0.f; v.z = 0.f; v.w = 0.f; }
    *(float4*)(a_lds + r * 256 + k4 * 4) = v;
    *(float4*)(out_masked + (size_t)m * 256 + k4 * 4) = v;
  }
  __syncthreads();

  // proj GEMM: thread (rg=t>>5, cg=t&31) owns rows rg*4..+3, cols cg+32*cc
  const int rg = t >> 5, cg = t & 31;
  float acc[4][8];
#pragma unroll
  for (int rr = 0; rr < 4; ++rr)
#pragma unroll
    for (int cc = 0; cc < 8; ++cc) acc[rr][cc] = 0.0f;

#pragma unroll 1
  for (int kc = 0; kc < 16; ++kc) {
#pragma unroll
    for (int i = 0; i < 4; ++i) {
      int e4 = i * 256 + t;
      int c = e4 >> 2, k4 = e4 & 3;
      float4 v = *(const float4*)(pw + c * 256 + kc * 16 + k4 * 4);
      *(float4*)(w_lds + c * 16 + ((k4 ^ ((c >> 1) & 3)) << 2)) = v;
    }
    __syncthreads();
#pragma unroll
    for (int k4 = 0; k4 < 4; ++k4) {
      float4 av[4];
#pragma unroll
      for (int rr = 0; rr < 4; ++rr)
        av[rr] = *(const float4*)(a_lds + (rg * 4 + rr) * 256 + kc * 16 + k4 * 4);
#pragma unroll
      for (int cc = 0; cc < 8; ++cc) {
        int c = cg + (cc << 5);
        float4 wv = *(const float4*)(w_lds + c * 16 + ((k4 ^ ((c >> 1) & 3)) << 2));
#pragma unroll
        for (int rr = 0; rr < 4; ++rr) {
          acc[rr][cc] = fmaf(av[rr].x, wv.x, acc[rr][cc]);
          acc[rr][cc] = fmaf(av[rr].y, wv.y, acc[rr][cc]);
          acc[rr][cc] = fmaf(av[rr].z, wv.z, acc[rr][cc]);
          acc[rr][cc] = fmaf(av[rr].w, wv.w, acc[rr][cc]);
        }
      }
    }
    __syncthreads();
  }

  // bias + LayerNorm (fp32 — screening only)
#pragma unroll
  for (int rr = 0; rr < 4; ++rr) {
#pragma unroll
    for (int cc = 0; cc < 8; ++cc) acc[rr][cc] += pb[cg + (cc << 5)];
    float s = 0.0f;
#pragma unroll
    for (int cc = 0; cc < 8; ++cc) s += acc[rr][cc];
    s += __shfl_xor(s, 1); s += __shfl_xor(s, 2); s += __shfl_xor(s, 4);
    s += __shfl_xor(s, 8); s += __shfl_xor(s, 16);
    float mu = s * (1.0f / 256.0f);
    float v = 0.0f;
#pragma unroll
    for (int cc = 0; cc < 8; ++cc) { float d = acc[rr][cc] - mu; v += d * d; }
    v += __shfl_xor(v, 1); v += __shfl_xor(v, 2); v += __shfl_xor(v, 4);
    v += __shfl_xor(v, 8); v += __shfl_xor(v, 16);
    float rs = 1.0f / sqrtf(v * (1.0f / 256.0f) + 1e-5f);
#pragma unroll
    for (int cc = 0; cc < 8; ++cc) {
      int c = cg + (cc << 5);
      acc[rr][cc] = (acc[rr][cc] - mu) * rs * g[c] + bt[c];
    }
  }

  // write encoded back into a_lds
#pragma unroll
  for (int rr = 0; rr < 4; ++rr)
#pragma unroll
    for (int cc = 0; cc < 8; ++cc)
      a_lds[(rg * 4 + rr) * 256 + cg + (cc << 5)] = acc[rr][cc];
  __syncthreads();

  // score GEMM: thread (rg2=t>>4, cq=t&15) rows rg2*2..+1, cols cq*5..+4
  const int rg2 = t >> 4, cq = t & 15;
  float acc2[2][5];
#pragma unroll
  for (int rr = 0; rr < 2; ++rr)
#pragma unroll
    for (int cc = 0; cc < 5; ++cc) acc2[rr][cc] = 0.0f;

#pragma unroll 1
  for (int kc = 0; kc < 16; ++kc) {
#pragma unroll
    for (int i = 0; i < 2; ++i) {
      int e4 = i * 256 + t;
      if (e4 < 320) {  // 80 cols * 4 float4
        int c = e4 >> 2, k4 = e4 & 3;
        float4 v = *(const float4*)(sw + c * 256 + kc * 16 + k4 * 4);
        *(float4*)(w_lds + c * 16 + ((k4 ^ ((c >> 1) & 3)) << 2)) = v;
      }
    }
    __syncthreads();
#pragma unroll
    for (int k4 = 0; k4 < 4; ++k4) {
      float4 ev[2];
      ev[0] = *(const float4*)(a_lds + (rg2 * 2 + 0) * 256 + kc * 16 + k4 * 4);
      ev[1] = *(const float4*)(a_lds + (rg2 * 2 + 1) * 256 + kc * 16 + k4 * 4);
#pragma unroll
      for (int cc = 0; cc < 5; ++cc) {
        int c = cq * 5 + cc;
        float4 wv = *(const float4*)(w_lds + c * 16 + ((k4 ^ ((c >> 1) & 3)) << 2));
#pragma unroll
        for (int rr = 0; rr < 2; ++rr) {
          acc2[rr][cc] = fmaf(ev[rr].x, wv.x, acc2[rr][cc]);
          acc2[rr][cc] = fmaf(ev[rr].y, wv.y, acc2[rr][cc]);
          acc2[rr][cc] = fmaf(ev[rr].z, wv.z, acc2[rr][cc]);
          acc2[rr][cc] = fmaf(ev[rr].w, wv.w, acc2[rr][cc]);
        }
      }
    }
    __syncthreads();
  }

  float mx0 = -3.4e38f, mx1 = -3.4e38f;
#pragma unroll
  for (int cc = 0; cc < 5; ++cc) {
    float b0 = acc2[0][cc] + sb[cq * 5 + cc];
    float b1 = acc2[1][cc] + sb[cq * 5 + cc];
    mx0 = fmaxf(mx0, b0); mx1 = fmaxf(mx1, b1);
  }
#pragma unroll
  for (int msk = 1; msk <= 8; msk <<= 1) {
    mx0 = fmaxf(mx0, __shfl_xor(mx0, msk));
    mx1 = fmaxf(mx1, __shfl_xor(mx1, msk));
  }
  if (cq == 0) {
    rowmax32[m0 + rg2 * 2 + 0] = mx0;
    rowmax32[m0 + rg2 * 2 + 1] = mx1;
  }
}

// ===================== Pass B: per-batch fp32 radix-select + candidate collect ========
extern "C" __global__ __launch_bounds__(256)
void k_select(const float* __restrict__ rowmax32, int* __restrict__ cand_idx,
              int* __restrict__ cand_cnt)
{
  __shared__ unsigned int keys[kS];
  __shared__ int red[4];
  __shared__ int sTotal;
  __shared__ int sCnt;
  const int t = threadIdx.x;
  const int b = blockIdx.x;

  for (int i = t; i < kS; i += 256)
    keys[i] = key32(rowmax32[(size_t)b * kS + i]);
  if (t == 0) sCnt = 0;
  __syncthreads();

  // radix select: T = key of the 300th largest
  unsigned int T = 0;
  for (int bit = 31; bit >= 0; --bit) {
    unsigned int cand = T | (1u << bit);
    int local = 0;
    for (int i = t; i < kS; i += 256) local += (keys[i] >= cand) ? 1 : 0;
#pragma unroll
    for (int msk = 1; msk <= 32; msk <<= 1) local += __shfl_xor(local, msk);
    if ((t & 63) == 0) red[t >> 6] = local;
    __syncthreads();
    if (t == 0) sTotal = red[0] + red[1] + red[2] + red[3];
    __syncthreads();
    if (sTotal >= kQ) T = cand;
    __syncthreads();
  }

  const float thr = dec32(T) - 1e-3f;  // eps margin >> fp32 score error
  for (int i = t; i < kS; i += 256) {
    if (dec32(keys[i]) >= thr) {
      int p = atomicAdd(&sCnt, 1);
      if (p < kCandCap) cand_idx[b * kCandCap + p] = i;
    }
  }
  __syncthreads();
  if (t == 0) cand_cnt[b] = (sCnt < kCandCap) ? sCnt : kCandCap;
}

// ===================== Pass C: fp64 re-encode + score for candidates only =============
// 16 candidate rows per block, 256 threads (same numerics as round-4 k_encode).
// Output indexed by candidate SLOT (b*kCandCap+q), not spatial index -> small ws.
extern "C" __global__ __launch_bounds__(256)
void k_rescore(const float* __restrict__ mem, const int* __restrict__ cand_idx,
               const int* __restrict__ cand_cnt,
               const float* __restrict__ pw, const float* __restrict__ pb,
               const float* __restrict__ g, const float* __restrict__ bt,
               const float* __restrict__ sw, const float* __restrict__ sb,
               double* __restrict__ rowmax64c)
{
  __shared__ float a_lds[16 * 256];
  __shared__ float w_lds[256 * 32];
  const int t = threadIdx.x;
  const int b = blockIdx.x >> 6;
  const int g0 = (blockIdx.x & 63) * 16;
  const int cnt = cand_cnt[b];
  if (g0 >= cnt) return;

  // gather 16 candidate rows (masked)
#pragma unroll
  for (int i = 0; i < 4; ++i) {
    int f4 = i * 256 + t;
    int r = f4 >> 6, k4 = f4 & 63;
    int q = g0 + r;
    float4 v = {0.f, 0.f, 0.f, 0.f};
    if (q < cnt) {
      int s = cand_idx[b * kCandCap + q];
      if (valid_s(s))
        v = *(const float4*)(mem + ((size_t)b * kS + s) * 256 + k4 * 4);
    }
    *(float4*)(a_lds + r * 256 + k4 * 4) = v;
  }
  __syncthreads();

  const int rg = t >> 5, cg = t & 31;
  double acc[2][8];
#pragma unroll
  for (int rr = 0; rr < 2; ++rr)
#pragma unroll
    for (int cc = 0; cc < 8; ++cc) acc[rr][cc] = 0.0;

#pragma unroll 1
  for (int kc = 0; kc < 8; ++kc) {
#pragma unroll
    for (int i = 0; i < 8; ++i) {
      int e4 = i * 256 + t;
      int c = e4 >> 3, k4 = e4 & 7;
      float4 v = *(const float4*)(pw + c * 256 + kc * 32 + k4 * 4);
      *(float4*)(w_lds + c * 32 + ((k4 ^ (c & 7)) << 2)) = v;
    }
    __syncthreads();
#pragma unroll
    for (int k4 = 0; k4 < 8; ++k4) {
      float4 av[2];
#pragma unroll
      for (int rr = 0; rr < 2; ++rr)
        av[rr] = *(const float4*)(a_lds + (rg * 2 + rr) * 256 + kc * 32 + k4 * 4);
#pragma unroll
      for (int cc = 0; cc < 8; ++cc) {
        int c = cg + (cc << 5);
        float4 wv = *(const float4*)(w_lds + c * 32 + ((k4 ^ (c & 7)) << 2));
#pragma unroll
        for (int rr = 0; rr < 2; ++rr) {
          acc[rr][cc] = fma((double)av[rr].x, (double)wv.x, acc[rr][cc]);
          acc[rr][cc] = fma((double)av[rr].y, (double)wv.y, acc[rr][cc]);
          acc[rr][cc] = fma((double)av[rr].z, (double)wv.z, acc[rr][cc]);
          acc[rr][cc] = fma((double)av[rr].w, (double)wv.w, acc[rr][cc]);
        }
      }
    }
    __syncthreads();
  }

#pragma unroll
  for (int rr = 0; rr < 2; ++rr) {
#pragma unroll
    for (int cc = 0; cc < 8; ++cc) acc[rr][cc] += (double)pb[cg + (cc << 5)];
    double s = 0.0;
#pragma unroll
    for (int cc = 0; cc < 8; ++cc) s += acc[rr][cc];
    s += __shfl_xor(s, 1); s += __shfl_xor(s, 2); s += __shfl_xor(s, 4);
    s += __shfl_xor(s, 8); s += __shfl_xor(s, 16);
    double mu = s * (1.0 / 256.0);
    double v = 0.0;
#pragma unroll
    for (int cc = 0; cc < 8; ++cc) { double d = acc[rr][cc] - mu; v += d * d; }
    v += __shfl_xor(v, 1); v += __shfl_xor(v, 2); v += __shfl_xor(v, 4);
    v += __shfl_xor(v, 8); v += __shfl_xor(v, 16);
    double rs = 1.0 / sqrt(v * (1.0 / 256.0) + 1e-5);
#pragma unroll
    for (int cc = 0; cc < 8; ++cc) {
      int c = cg + (cc << 5);
      acc[rr][cc] = (acc[rr][cc] - mu) * rs * (double)g[c] + (double)bt[c];
    }
  }

  // hi/lo split of encoded
  float* hi_lds = a_lds;
  float* lo_lds = w_lds;
#pragma unroll
  for (int rr = 0; rr < 2; ++rr)
#pragma unroll
    for (int cc = 0; cc < 8; ++cc) {
      int idx = (rg * 2 + rr) * 256 + cg + (cc << 5);
      float h = (float)acc[rr][cc];
      hi_lds[idx] = h;
      lo_lds[idx] = (float)(acc[rr][cc] - (double)h);
    }
  __syncthreads();

  // fp64 score + rowmax
  const int row = t >> 4, cq = t & 15;
  double acc2[5] = {0.0, 0.0, 0.0, 0.0, 0.0};
#pragma unroll 4
  for (int k4 = 0; k4 < 64; ++k4) {
    float4 hv = *(const float4*)(hi_lds + row * 256 + k4 * 4);
    float4 lv = *(const float4*)(lo_lds + row * 256 + k4 * 4);
#pragma unroll
    for (int cc = 0; cc < 5; ++cc) {
      int c = cq * 5 + cc;
      float4 wv = *(const float4*)(sw + c * 256 + k4 * 4);
      acc2[cc] = fma((double)hv.x, (double)wv.x, fma((double)lv.x, (double)wv.x, acc2[cc]));
      acc2[cc] = fma((double)hv.y, (double)wv.y, fma((double)lv.y, (double)wv.y, acc2[cc]));
      acc2[cc] = fma((double)hv.z, (double)wv.z, fma((double)lv.z, (double)wv.z, acc2[cc]));
      acc2[cc] = fma((double)hv.w, (double)wv.w, fma((double)lv.w, (double)wv.w, acc2[cc]));
    }
  }
  double rmax = -1.0e300;
#pragma unroll
  for (int cc = 0; cc < 5; ++cc) {
    double sc = acc2[cc] + (double)sb[cq * 5 + cc];
    rmax = fmax(rmax, sc);
  }
  rmax = fmax(rmax, __shfl_xor(rmax, 1));
  rmax = fmax(rmax, __shfl_xor(rmax, 2));
  rmax = fmax(rmax, __shfl_xor(rmax, 4));
  rmax = fmax(rmax, __shfl_xor(rmax, 8));
  int q = g0 + row;
  if (cq == 0 && q < cnt)
    rowmax64c[(size_t)b * kCandCap + q] = rmax;
}

// ===================== Pass D: sort candidates on fp64 keys -> top-300 ================
extern "C" __global__ __launch_bounds__(1024)
void k_topk2(const double* __restrict__ rowmax64c, const int* __restrict__ cand_idx,
             const int* __restrict__ cand_cnt, int* __restrict__ topk)
{
  __shared__ unsigned long long ckey[kCandCap];
  __shared__ unsigned int cidx[kCandCap];
  const int t = threadIdx.x;
  const int b = blockIdx.x;
  const int cnt = cand_cnt[b];

  if (t < cnt) {
    ckey[t] = key64(rowmax64c[(size_t)b * kCandCap + t]);
    cidx[t] = (unsigned int)cand_idx[b * kCandCap + t];
  } else {
    ckey[t] = 0ull;
    cidx[t] = 0xFFFFFFFFu;
  }
  __syncthreads();

  // bitonic sort: descending by key; equal key -> ascending index (lax.top_k)
  for (int ksz = 2; ksz <= kCandCap; ksz <<= 1) {
    for (int j = ksz >> 1; j > 0; j >>= 1) {
      int ixj = t ^ j;
      if (ixj > t) {
        unsigned long long ka = ckey[t], kb = ckey[ixj];
        unsigned int ia = cidx[t], ib = cidx[ixj];
        bool desc = ((t & ksz) == 0);
        bool lessAB = (ka < kb) || (ka == kb && ia > ib);
        bool lessBA = (kb < ka) || (ka == kb && ib > ia);
        bool do_swap = desc ? lessAB : lessBA;
        if (do_swap) { ckey[t] = kb; ckey[ixj] = ka; cidx[t] = ib; cidx[ixj] = ia; }
      }
      __syncthreads();
    }
  }
  if (t < kQ) topk[b * kQ + t] = (int)cidx[t];
}

// ===================== fp32 helpers for kernel E (unchanged) =====================
__device__ __forceinline__ void gemm_nk256(const float* __restrict__ W,
                                           const float* __restrict__ a_lds,
                                           float* __restrict__ w_lds,
                                           float acc[4][8], int rg, int cg, int t)
{
#pragma unroll
  for (int rr = 0; rr < 4; ++rr)
#pragma unroll
    for (int cc = 0; cc < 8; ++cc) acc[rr][cc] = 0.0f;

#pragma unroll 1
  for (int kc = 0; kc < 8; ++kc) {
#pragma unroll
    for (int i = 0; i < 8; ++i) {
      int e4 = i * 256 + t;
      int c = e4 >> 3, k4 = e4 & 7;
      float4 v = *(const float4*)(W + c * 256 + kc * 32 + k4 * 4);
      *(float4*)(w_lds + c * 32 + ((k4 ^ (c & 7)) << 2)) = v;
    }
    __syncthreads();
#pragma unroll
    for (int k4 = 0; k4 < 8; ++k4) {
      float4 av[4];
#pragma unroll
      for (int rr = 0; rr < 4; ++rr)
        av[rr] = *(const float4*)(a_lds + (rg * 4 + rr) * 256 + kc * 32 + k4 * 4);
#pragma unroll
      for (int cc = 0; cc < 8; ++cc) {
        int c = cg + (cc << 5);
        float4 wv = *(const float4*)(w_lds + c * 32 + ((k4 ^ (c & 7)) << 2));
#pragma unroll
        for (int rr = 0; rr < 4; ++rr) {
          acc[rr][cc] = fmaf(av[rr].x, wv.x, acc[rr][cc]);
          acc[rr][cc] = fmaf(av[rr].y, wv.y, acc[rr][cc]);
          acc[rr][cc] = fmaf(av[rr].z, wv.z, acc[rr][cc]);
          acc[rr][cc] = fmaf(av[rr].w, wv.w, acc[rr][cc]);
        }
      }
    }
    __syncthreads();
  }
}

__device__ __forceinline__ void gemm_score(const float* __restrict__ SW,
                                           const float* __restrict__ a_lds,
                                           float* __restrict__ w_lds,
                                           float acc2[2][5], int rg2, int cq, int t)
{
#pragma unroll
  for (int rr = 0; rr < 2; ++rr)
#pragma unroll
    for (int cc = 0; cc < 5; ++cc) acc2[rr][cc] = 0.0f;

#pragma unroll 1
  for (int kc = 0; kc < 8; ++kc) {
#pragma unroll
    for (int i = 0; i < 3; ++i) {
      int e4 = i * 256 + t;
      if (e4 < 640) {
        int c = e4 >> 3, k4 = e4 & 7;
        float4 v = *(const float4*)(SW + c * 256 + kc * 32 + k4 * 4);
        *(float4*)(w_lds + c * 32 + ((k4 ^ (c & 7)) << 2)) = v;
      }
    }
    __syncthreads();
#pragma unroll
    for (int k4 = 0; k4 < 8; ++k4) {
      float4 ev[2];
      ev[0] = *(const float4*)(a_lds + (rg2 * 2 + 0) * 256 + kc * 32 + k4 * 4);
      ev[1] = *(const float4*)(a_lds + (rg2 * 2 + 1) * 256 + kc * 32 + k4 * 4);
#pragma unroll
      for (int cc = 0; cc < 5; ++cc) {
        int c = cq * 5 + cc;
        float4 wv = *(const float4*)(w_lds + c * 32 + ((k4 ^ (c & 7)) << 2));
#pragma unroll
        for (int rr = 0; rr < 2; ++rr) {
          acc2[rr][cc] = fmaf(ev[rr].x, wv.x, acc2[rr][cc]);
          acc2[rr][cc] = fmaf(ev[rr].y, wv.y, acc2[rr][cc]);
          acc2[rr][cc] = fmaf(ev[rr].z, wv.z, acc2[rr][cc]);
          acc2[rr][cc] = fmaf(ev[rr].w, wv.w, acc2[rr][cc]);
        }
      }
    }
    __syncthreads();
  }
}

__device__ __forceinline__ void apply_ln(float acc[4][8], const float* __restrict__ g,
                                         const float* __restrict__ bt, int cg)
{
#pragma unroll
  for (int rr = 0; rr < 4; ++rr) {
    float s = 0.0f;
#pragma unroll
    for (int cc = 0; cc < 8; ++cc) s += acc[rr][cc];
    s += __shfl_xor(s, 1); s += __shfl_xor(s, 2); s += __shfl_xor(s, 4);
    s += __shfl_xor(s, 8); s += __shfl_xor(s, 16);
    float mu = s * (1.0f / 256.0f);
    float v = 0.0f;
#pragma unroll
    for (int cc = 0; cc < 8; ++cc) { float d = acc[rr][cc] - mu; v += d * d; }
    v += __shfl_xor(v, 1); v += __shfl_xor(v, 2); v += __shfl_xor(v, 4);
    v += __shfl_xor(v, 8); v += __shfl_xor(v, 16);
    float rs = 1.0f / sqrtf(v * (1.0f / 256.0f) + 1e-5f);
#pragma unroll
    for (int cc = 0; cc < 8; ++cc) {
      int c = cg + (cc << 5);
      acc[rr][cc] = (acc[rr][cc] - mu) * rs * g[c] + bt[c];
    }
  }
}

// ===================== Pass E: gathered re-encode + box MLP + outputs =================
extern "C" __global__ __launch_bounds__(256)
void k_boxes(const float* __restrict__ mem, const int* __restrict__ topk,
             const float* __restrict__ pw, const float* __restrict__ pb,
             const float* __restrict__ g, const float* __restrict__ bt,
             const float* __restrict__ sw, const float* __restrict__ sb,
             const float* __restrict__ w1, const float* __restrict__ b1,
             const float* __restrict__ w2, const float* __restrict__ b2,
             const float* __restrict__ w3, const float* __restrict__ b3,
             float* __restrict__ out_tgt, float* __restrict__ out_ref,
             float* __restrict__ out_box, float* __restrict__ out_log)
{
  __shared__ float a_lds[32 * 256];
  __shared__ float w_lds[256 * 32];
  const int t = threadIdx.x;
  const int r0g = blockIdx.x * 32;

#pragma unroll
  for (int i = 0; i < 8; ++i) {
    int f4 = i * 256 + t;
    int r = f4 >> 6, k4 = f4 & 63;
    int rgid = r0g + r;
    int bb = rgid / kQ;
    int s = topk[rgid];
    float4 v = *(const float4*)(mem + ((size_t)bb * kS + s) * 256 + k4 * 4);
    if (!valid_s(s)) { v.x = 0.f; v.y = 0.f; v.z = 0.f; v.w = 0.f; }
    *(float4*)(a_lds + r * 256 + k4 * 4) = v;
  }

  const int rg = t >> 5, cg = t & 31;
  float acc[4][8];
  gemm_nk256(pw, a_lds, w_lds, acc, rg, cg, t);
#pragma unroll
  for (int rr = 0; rr < 4; ++rr)
#pragma unroll
    for (int cc = 0; cc < 8; ++cc) acc[rr][cc] += pb[cg + (cc << 5)];
  apply_ln(acc, g, bt, cg);
#pragma unroll
  for (int rr = 0; rr < 4; ++rr)
#pragma unroll
    for (int cc = 0; cc < 8; ++cc)
      a_lds[(rg * 4 + rr) * 256 + cg + (cc << 5)] = acc[rr][cc];
  __syncthreads();

#pragma unroll
  for (int i = 0; i < 8; ++i) {
    int f4 = i * 256 + t;
    int r = f4 >> 6, k4 = f4 & 63;
    *(float4*)(out_tgt + (size_t)(r0g + r) * 256 + k4 * 4) =
        *(const float4*)(a_lds + r * 256 + k4 * 4);
  }

  const int rg2 = t >> 4, cq = t & 15;
  float acc2[2][5];
  gemm_score(sw, a_lds, w_lds, acc2, rg2, cq, t);
#pragma unroll
  for (int rr = 0; rr < 2; ++rr)
#pragma unroll
    for (int cc = 0; cc < 5; ++cc) {
      int c = cq * 5 + cc;
      out_log[(size_t)(r0g + rg2 * 2 + rr) * kC + c] = acc2[rr][cc] + sb[c];
    }

  gemm_nk256(w1, a_lds, w_lds, acc, rg, cg, t);
#pragma unroll
  for (int rr = 0; rr < 4; ++rr)
#pragma unroll
    for (int cc = 0; cc < 8; ++cc) {
      float v = acc[rr][cc] + b1[cg + (cc << 5)];
      a_lds[(rg * 4 + rr) * 256 + cg + (cc << 5)] = fmaxf(v, 0.0f);
    }
  __syncthreads();

  gemm_nk256(w2, a_lds, w_lds, acc, rg, cg, t);
#pragma unroll
  for (int rr = 0; rr < 4; ++rr)
#pragma unroll
    for (int cc = 0; cc < 8; ++cc) {
      float v = acc[rr][cc] + b2[cg + (cc << 5)];
      a_lds[(rg * 4 + rr) * 256 + cg + (cc << 5)] = fmaxf(v, 0.0f);
    }
  __syncthreads();

  if (t < 128) {
    int r = t >> 2, c = t & 3;
    float accb = 0.0f;
#pragma unroll 4
    for (int k4 = 0; k4 < 64; ++k4) {
      float4 hv = *(const float4*)(a_lds + r * 256 + k4 * 4);
      float4 wv = *(const float4*)(w3 + c * 256 + k4 * 4);
      accb = fmaf(hv.x, wv.x, accb);
      accb = fmaf(hv.y, wv.y, accb);
      accb = fmaf(hv.z, wv.z, accb);
      accb = fmaf(hv.w, wv.w, accb);
    }
    int rgid = r0g + r;
    int s = topk[rgid];
    float bu = accb + b3[c] + anchor_component(s, c);
    out_ref[(size_t)rgid * 4 + c] = bu;
    out_box[(size_t)rgid * 4 + c] = 1.0f / (1.0f + expf(-bu));
  }
}

extern "C" void kernel_launch(void* const* d_in, const int* in_sizes, int n_in,
                              void* d_out, int out_size, void* d_ws, size_t ws_size,
                              hipStream_t stream) {
  (void)in_sizes; (void)n_in; (void)out_size; (void)ws_size;
  const float* mem = (const float*)d_in[0];
  const float* pw = (const float*)d_in[2];
  const float* pb = (const float*)d_in[3];
  const float* g  = (const float*)d_in[4];
  const float* bt = (const float*)d_in[5];
  const float* sw = (const float*)d_in[6];
  const float* sb = (const float*)d_in[7];
  const float* w1 = (const float*)d_in[8];
  const float* b1 = (const float*)d_in[9];
  const float* w2 = (const float*)d_in[10];
  const float* b2 = (const float*)d_in[11];
  const float* w3 = (const float*)d_in[12];
  const float* b3 = (const float*)d_in[13];

  float* out = (float*)d_out;
  float* out_tgt = out + OFF_TGT;
  float* out_ref = out + OFF_REF;
  float* out_box = out + OFF_BOX;
  float* out_log = out + OFF_LOG;
  float* out_msk = out + OFF_MSK;

  // workspace layout (total ~1.5 MB, within the round-4-proven envelope)
  char* ws = (char*)d_ws;
  float*  rowmax32  = (float*)ws;                        ws += (size_t)kNB * kS * sizeof(float);
  double* rowmax64c = (double*)ws;                       ws += (size_t)kNB * kCandCap * sizeof(double);
  int*    cand_idx  = (int*)ws;                          ws += (size_t)kNB * kCandCap * sizeof(int);
  int*    cand_cnt  = (int*)ws;                          ws += (size_t)kNB * sizeof(int);
  int*    topk      = (int*)ws;

  k_encode32<<<dim3(kNB * kS / 32), dim3(256), 0, stream>>>(mem, pw, pb, g, bt, sw, sb,
                                                            out_msk, rowmax32);
  k_select<<<dim3(kNB), dim3(256), 0, stream>>>(rowmax32, cand_idx, cand_cnt);
  k_rescore<<<dim3(kNB * 64), dim3(256), 0, stream>>>(mem, cand_idx, cand_cnt,
                                                      pw, pb, g, bt, sw, sb, rowmax64c);
  k_topk2<<<dim3(kNB), dim3(1024), 0, stream>>>(rowmax64c, cand_idx, cand_cnt, topk);
  k_boxes<<<dim3(kNB * kQ / 32), dim3(256), 0, stream>>>(mem, topk, pw, pb, g, bt, sw, sb,
                                                         w1, b1, w2, b2, w3, b3,
                                                         out_tgt, out_ref, out_box, out_log);
}